// Round 9
// baseline (185.717 us; speedup 1.0000x reference)
//
#include <hip/hip_runtime.h>
#include <hip/hip_bf16.h>

// Problem constants
#define BB 128        // batch
#define NN 100000     // memory bank size
#define DD 256        // feat dim (K)
#define CC 2000       // num classes
#define SS 751        // source classes
#define INVTEMP 20.0f // 1/0.05
#define EPSV 1e-6f

#define HIST_BLOCKS 391   // ceil(100000/256)
#define PREP_BLOCKS 16    // 4096/256 (inputs-only fragments)
#define NTILES 1563       // ceil(NN/64)

typedef __attribute__((ext_vector_type(8))) short bf16x8;
typedef __attribute__((ext_vector_type(8))) unsigned short u16x8;
typedef __attribute__((ext_vector_type(4))) float f32x4;

__device__ __forceinline__ unsigned short f2bf(float x) {
    unsigned int u = __float_as_uint(x);
    u += 0x7fffu + ((u >> 16) & 1u);   // round-to-nearest-even
    return (unsigned short)(u >> 16);
}

__device__ __forceinline__ u16x8 pack8(float4 a, float4 b) {
    u16x8 o;
    o[0] = f2bf(a.x); o[1] = f2bf(a.y); o[2] = f2bf(a.z); o[3] = f2bf(a.w);
    o[4] = f2bf(b.x); o[5] = f2bf(b.y); o[6] = f2bf(b.z); o[7] = f2bf(b.w);
    return o;
}

// monotone float -> uint key (for atomicMax/Min); init 0x00000000 = -inf, 0xFFFFFFFF = +inf
__device__ __forceinline__ unsigned fkey(float f) {
    unsigned b = __float_as_uint(f);
    return (b & 0x80000000u) ? ~b : (b | 0x80000000u);
}
__device__ __forceinline__ float finv(unsigned k) {
    unsigned b = (k & 0x80000000u) ? (k ^ 0x80000000u) : ~k;
    return __uint_as_float(b);
}

// ---------------- fused: histogram + inputs-fragment prep (inputs ONLY) ----------------
// inb: 16B chunk ch = (nr*8 + kc)*64 + l holds row nr*16+(l&15) (0..127 = inputs),
// k = kc*32 + (l>>4)*8 + j. 4096 chunks = 64 KB.
__global__ __launch_bounds__(256) void hist_prep_kernel(
    const int* __restrict__ labels, int* __restrict__ counts,
    const float* __restrict__ in1, unsigned short* __restrict__ inb)
{
    int bid = blockIdx.x;
    if (bid < HIST_BLOCKS) {
        int n = bid * 256 + threadIdx.x;
        if (n < NN) atomicAdd(&counts[labels[n]], 1);
    } else {
        int ch = (bid - HIST_BLOCKS) * 256 + threadIdx.x;  // 0..4095
        int l  = ch & 63;
        int kc = (ch >> 6) & 7;
        int nr = ch >> 9;                                   // 0..7
        int row = nr * 16 + (l & 15);                       // 0..127
        const float* src = in1 + (size_t)row * DD;
        int k0 = kc * 32 + ((l >> 4) << 3);
        u16x8 o;
        #pragma unroll
        for (int j = 0; j < 8; ++j) o[j] = f2bf(src[k0 + j]);
        *(u16x8*)(inb + (size_t)ch * 8) = o;
    }
}

// one block, 256 threads, exclusive scan over 2048 (padded) counts; also zeroes out
__global__ __launch_bounds__(256) void scan_kernel(const int* __restrict__ counts,
                                                   int* __restrict__ offsets,
                                                   int* __restrict__ cursor,
                                                   float* __restrict__ out) {
    const int PT = 8;
    int tid = threadIdx.x;
    if (tid == 0) { out[0] = 0.f; out[1] = 0.f; }
    int vals[PT];
    int tot = 0;
    #pragma unroll
    for (int i = 0; i < PT; ++i) {
        int c = tid * PT + i;
        vals[i] = (c < CC) ? counts[c] : 0;
        tot += vals[i];
    }
    __shared__ int sh[256];
    sh[tid] = tot;
    __syncthreads();
    for (int ofs = 1; ofs < 256; ofs <<= 1) {
        int v = (tid >= ofs) ? sh[tid - ofs] : 0;
        __syncthreads();
        sh[tid] += v;
        __syncthreads();
    }
    int run = sh[tid] - tot;
    #pragma unroll
    for (int i = 0; i < PT; ++i) {
        int c = tid * PT + i;
        if (c < CC) { offsets[c] = run; cursor[c] = run; }
        run += vals[i];
    }
}

// ---------------- fused scatter + f32->bf16 conversion + sorted class ids ----------------
__global__ __launch_bounds__(256) void scatter_conv(
    const int* __restrict__ labels, int* __restrict__ cursor,
    const float* __restrict__ features, unsigned short* __restrict__ featbf,
    int* __restrict__ cls_sorted)
{
    int t = blockIdx.x * 256 + threadIdx.x;
    int n = t >> 3;        // bank row
    int g = t & 7;         // lane within row-group
    if (n >= NN) return;
    int c = labels[n];
    int p = 0;
    if (g == 0) p = atomicAdd(&cursor[c], 1);
    p = __shfl(p, (threadIdx.x & 63) & ~7, 64);   // broadcast leader's slot
    if (g == 0) cls_sorted[p] = c;

    const float4* src = (const float4*)(features + (size_t)n * DD) + g * 8; // 128 B
    unsigned short* dst = featbf + (size_t)p * 256 + g * 32;                // 64 B
    #pragma unroll
    for (int i = 0; i < 4; ++i) {
        float4 a = src[2 * i], b = src[2 * i + 1];
        *(u16x8*)(dst + i * 8) = pack8(a, b);
    }
}

// ---------------- fc_sim: per-class feature sum + sim/sim2 dot (c < SS only) ----------------
// segment_sum(logits)/cnt == (sum of class features)·x * INVTEMP/cnt — no per-member
// logits needed for the sums. Block = class (751), 256 threads.
__global__ __launch_bounds__(256) void fc_sim(
    const unsigned short* __restrict__ featbf,
    const int* __restrict__ offsets, const int* __restrict__ counts,
    const float* __restrict__ inputs, const float* __restrict__ inputs2,
    float* __restrict__ simA, float* __restrict__ simB)
{
    const int c   = blockIdx.x;   // 0..SS-1
    const int t   = threadIdx.x;
    const int cnt = counts[c], off = offsets[c];

    __shared__ float F[DD];
    float acc = 0.f;
    for (int i = 0; i < cnt; ++i) {
        unsigned short u = featbf[(size_t)(off + i) * DD + t];
        acc += __uint_as_float((unsigned)u << 16);
    }
    F[t] = acc;
    __syncthreads();

    const float* x = (t < BB) ? (inputs + (size_t)t * DD)
                              : (inputs2 + (size_t)(t - BB) * DD);
    float s = 0.f;
    #pragma unroll 4
    for (int k = 0; k < DD; k += 4) {
        float4 Fv = *(const float4*)&F[k];
        float4 xv = *(const float4*)(x + k);
        s += Fv.x * xv.x + Fv.y * xv.y + Fv.z * xv.z + Fv.w * xv.w;
    }
    s *= INVTEMP / (float)(cnt > 0 ? cnt : 1);
    if (t < BB) simA[(size_t)t * SS + c] = s;
    else        simB[(size_t)(t - BB) * SS + c] = s;
}

// ---------------- heavy kernel: flat GEMM over sorted bank + segment max/min ----------------
// Grid = NTILES blocks x 256 threads (4 waves). Block b: rows [64b, 64b+64) of the
// class-sorted bank, all 128 inputs cols (wave w: cols 32w..+32, nb=0..1).
// A staged via global_load_lds into fragment-order LDS (r8-proven, 0 conflicts):
// frag (ma,kc) = 1KB, chunk l holds row 16ma+((l&15)^kc), k-bytes kc*64+(l>>4)*16;
// wave w stages ma=w (8 calls). After MFMA, logits dumped to LDS [64][128] f32
// (overlaying A) and 2 threads/col run a boundary-aware segment scan using
// cls_sorted, flushing per-class max/min via ordered-uint atomicMax/Min.
// ~116 regs, 32 KB LDS -> 3-4 blocks/CU co-resident: latency hidden by block TLP.
__global__ __launch_bounds__(256, 3) void minmax_kernel(
    const unsigned short* __restrict__ featbf, const unsigned short* __restrict__ inb,
    const int* __restrict__ cls_sorted,
    unsigned* __restrict__ gmaxu, unsigned* __restrict__ gminu)
{
    const int tid = threadIdx.x;
    const int w   = tid >> 6;
    const int l   = tid & 63;
    const int r0  = blockIdx.x * 64;

    __shared__ __align__(16) char ldsA[32768];   // A tile, then overlaid with logits
    __shared__ int cls[64];
    float* logit = (float*)ldsA;

    // hoist B (inputs) fragments: kc 0..7, nb 0..1 -> 16 x bf16x8 (64 VGPR)
    bf16x8 bfr[16];
    #pragma unroll
    for (int kc = 0; kc < 8; ++kc)
        #pragma unroll
        for (int nb = 0; nb < 2; ++nb) {
            int nr = 2 * w + nb;  // 0..7
            bfr[kc * 2 + nb] = *(const bf16x8*)(inb + (((size_t)(nr * 8 + kc) * 64 + l) << 3));
        }

    // stage class ids
    if (tid < 64) {
        int gr = r0 + tid;
        cls[tid] = (gr < NN) ? cls_sorted[gr] : -1;
    }

    // stage A: wave w stages fragments (ma=w, kc=0..7)
    const char* fb = (const char*)featbf;
    #pragma unroll
    for (int kc = 0; kc < 8; ++kc) {
        int row = 16 * w + ((l & 15) ^ kc);
        int gr  = min(r0 + row, NN - 1);                 // clamp (scan skips padded rows)
        const char* src = fb + ((size_t)gr << 9) + (kc << 6) + ((l >> 4) << 4);
        __builtin_amdgcn_global_load_lds(
            (const __attribute__((address_space(1))) void*)src,
            (__attribute__((address_space(3))) void*)(&ldsA[0] + ((w * 8 + kc) << 10)),
            16, 0, 0);
    }
    __syncthreads();

    // MFMA: acc[ma][nb] over kc
    f32x4 acc[4][2];
    #pragma unroll
    for (int ma = 0; ma < 4; ++ma)
        #pragma unroll
        for (int nb = 0; nb < 2; ++nb)
            acc[ma][nb] = (f32x4){0.f, 0.f, 0.f, 0.f};

    __builtin_amdgcn_s_setprio(1);
    #pragma unroll
    for (int kc = 0; kc < 8; ++kc) {
        int lx = (l ^ kc) << 4;
        #pragma unroll
        for (int ma = 0; ma < 4; ++ma) {
            bf16x8 a = *(const bf16x8*)(&ldsA[0] + ((ma * 8 + kc) << 10) + lx);
            acc[ma][0] = __builtin_amdgcn_mfma_f32_16x16x32_bf16(a, bfr[kc * 2 + 0], acc[ma][0], 0, 0, 0);
            acc[ma][1] = __builtin_amdgcn_mfma_f32_16x16x32_bf16(a, bfr[kc * 2 + 1], acc[ma][1], 0, 0, 0);
        }
    }
    __builtin_amdgcn_s_setprio(0);
    __syncthreads();   // all waves done reading A -> safe to overlay

    // dump logits to LDS [64 rows][128 cols] f32 (lane: col=16nb+32w+(l&15), row=16ma+4(l>>4)+reg)
    {
        int m = l & 15, h = l >> 4;
        #pragma unroll
        for (int ma = 0; ma < 4; ++ma)
            #pragma unroll
            for (int nb = 0; nb < 2; ++nb)
                #pragma unroll
                for (int reg = 0; reg < 4; ++reg) {
                    int row = 16 * ma + 4 * h + reg;
                    int col = 32 * w + 16 * nb + m;
                    logit[row * 128 + col] = acc[ma][nb][reg];
                }
    }
    __syncthreads();

    // segment scan: 2 threads per col, 32 rows each (class-sorted -> few boundaries)
    {
        int col  = tid & 127;
        int half = tid >> 7;
        int cur = -1;
        float mx = 0.f, mn = 0.f;
        for (int i = 0; i < 32; ++i) {
            int r = 32 * half + i;
            if (r0 + r >= NN) break;
            int c = cls[r];
            float v = logit[r * 128 + col];
            if (c != cur) {
                if (cur >= 0) {
                    atomicMax(&gmaxu[(size_t)col * CC + cur], fkey(mx));
                    atomicMin(&gminu[(size_t)col * CC + cur], fkey(mn));
                }
                cur = c; mx = v; mn = v;
            } else {
                mx = fmaxf(mx, v);
                mn = fminf(mn, v);
            }
        }
        if (cur >= 0) {
            atomicMax(&gmaxu[(size_t)col * CC + cur], fkey(mx));
            atomicMin(&gminu[(size_t)col * CC + cur], fkey(mn));
        }
    }
}

// ---------------- finalize: losses ----------------

__device__ __forceinline__ float blk_reduce_sum(float v) {
    __shared__ float sh[4];
    int lane = threadIdx.x & 63, w = threadIdx.x >> 6;
    #pragma unroll
    for (int o = 32; o; o >>= 1) v += __shfl_down(v, o, 64);
    __syncthreads();
    if (lane == 0) sh[w] = v;
    __syncthreads();
    return sh[0] + sh[1] + sh[2] + sh[3];
}

__device__ __forceinline__ float blk_reduce_max(float v) {
    __shared__ float sh[4];
    int lane = threadIdx.x & 63, w = threadIdx.x >> 6;
    #pragma unroll
    for (int o = 32; o; o >>= 1) v = fmaxf(v, __shfl_down(v, o, 64));
    __syncthreads();
    if (lane == 0) sh[w] = v;
    __syncthreads();
    return fmaxf(fmaxf(sh[0], sh[1]), fmaxf(sh[2], sh[3]));
}

__global__ __launch_bounds__(256) void finalize_kernel(
    const unsigned* __restrict__ gmaxu, const unsigned* __restrict__ gminu,
    const float* __restrict__ simA, const float* __restrict__ simB,
    const int* __restrict__ counts, const int* __restrict__ labels,
    const int* __restrict__ indexes, float* __restrict__ out)
{
    const int b   = blockIdx.x;
    const int tid = threadIdx.x;
    const int tgt = labels[indexes[b]];

    __shared__ float sh_etgt;
    float local = 0.f;
    for (int c = tid; c < CC; c += 256) {
        unsigned ku = (c == tgt) ? gminu[(size_t)b * CC + c] : gmaxu[(size_t)b * CC + c];
        float e = 0.f;
        if (counts[c] > 0) e = expf(finv(ku) * INVTEMP);
        local += e;
        if (c == tgt) sh_etgt = e;
    }
    float sum_e = blk_reduce_sum(local);
    float etgt = sh_etgt;
    float loss_con_b = -logf(etgt / (sum_e + EPSV) + EPSV);

    __shared__ float a1[SS], a2[SS];
    for (int c = tid; c < SS; c += 256) {
        a1[c] = simA[(size_t)b * SS + c];
        a2[c] = simB[(size_t)b * SS + c];
    }
    __syncthreads();
    float m1 = -3.4e38f, m2 = -3.4e38f;
    for (int c = tid; c < SS; c += 256) { m1 = fmaxf(m1, a1[c]); m2 = fmaxf(m2, a2[c]); }
    m1 = blk_reduce_max(m1);
    m2 = blk_reduce_max(m2);
    float s1 = 0.f, s2 = 0.f;
    for (int c = tid; c < SS; c += 256) { s1 += expf(a1[c] - m1); s2 += expf(a2[c] - m2); }
    s1 = blk_reduce_sum(s1);
    s2 = blk_reduce_sum(s2);
    float inv1 = 1.f / s1, inv2 = 1.f / s2;
    float dsum = 0.f;
    for (int c = tid; c < SS; c += 256) {
        float d = expf(a1[c] - m1) * inv1 - expf(a2[c] - m2) * inv2;
        dsum += d * d;
    }
    dsum = blk_reduce_sum(dsum);
    if (tid == 0) {
        atomicAdd(&out[0], loss_con_b * (1.0f / (float)BB));
        atomicAdd(&out[1], dsum * (1.0f / (float)SS));
    }
}

// ---------------- launch ----------------

extern "C" void kernel_launch(void* const* d_in, const int* in_sizes, int n_in,
                              void* d_out, int out_size, void* d_ws, size_t ws_size,
                              hipStream_t stream) {
    const float* inputs   = (const float*)d_in[0];
    const float* inputs2  = (const float*)d_in[1];
    const float* features = (const float*)d_in[2];
    const int*   labels   = (const int*)d_in[3];
    const int*   indexes  = (const int*)d_in[4];

    float* out = (float*)d_out;

    // workspace layout (int-element offsets)
    int* wsi = (int*)d_ws;
    int* counts  = wsi;                 // [0, 2048)
    int* offsets = wsi + 2048;          // [2048, 4096)
    int* cursor  = wsi + 4096;          // [4096, 6144)
    unsigned short* inb = (unsigned short*)(wsi + 6144);      // 32768 ushorts (64 KB) -> [6144, 22528)
    int* cls_sorted = wsi + 22528;                            // 100000 ints -> [22528, 122528)
    unsigned* gmaxu = (unsigned*)(wsi + 122528);              // CC*BB uints -> [122528, 378528)
    unsigned* gminu = (unsigned*)(wsi + 378528);              // [378528, 634528)
    float* simA = (float*)(wsi + 634528);                     // BB*SS -> [634528, 730656)
    float* simB = (float*)(wsi + 730656);                     // [730656, 826784)
    unsigned short* featbf = (unsigned short*)(wsi + 826784); // NN*256 ushorts = 51.2 MB

    hipMemsetAsync(counts, 0, 2048 * sizeof(int), stream);
    hipMemsetAsync(gmaxu, 0x00, (size_t)CC * BB * 4, stream); // key(-inf) floor
    hipMemsetAsync(gminu, 0xFF, (size_t)CC * BB * 4, stream); // key(+inf) ceiling

    hist_prep_kernel<<<HIST_BLOCKS + PREP_BLOCKS, 256, 0, stream>>>(
        labels, counts, inputs, inb);
    scan_kernel<<<1, 256, 0, stream>>>(counts, offsets, cursor, out);
    scatter_conv<<<(NN * 8 + 255) / 256, 256, 0, stream>>>(labels, cursor, features,
                                                           featbf, cls_sorted);
    fc_sim<<<SS, 256, 0, stream>>>(featbf, offsets, counts, inputs, inputs2, simA, simB);
    minmax_kernel<<<NTILES, 256, 0, stream>>>(featbf, inb, cls_sorted, gmaxu, gminu);
    finalize_kernel<<<BB, 256, 0, stream>>>(gmaxu, gminu, simA, simB, counts,
                                            labels, indexes, out);
}

// Round 10
// 130.322 us; speedup vs baseline: 1.4251x; 1.4251x over previous
//
#include <hip/hip_runtime.h>
#include <hip/hip_bf16.h>

// Problem constants
#define BB 128        // batch
#define NN 100000     // memory bank size
#define DD 256        // feat dim (K)
#define CC 2000       // num classes
#define SS 751        // source classes
#define INVTEMP 20.0f // 1/0.05
#define EPSV 1e-6f

#define HIST_BLOCKS 391   // ceil(100000/256)
#define PREP_BLOCKS 32    // 8192/256 (inputs + inputs2 fragments)
#define NTILES 1563       // ceil(NN/64)
#define MAXSEG 8          // max class segments per 64-row tile (data: <=4)

typedef __attribute__((ext_vector_type(8))) short bf16x8;
typedef __attribute__((ext_vector_type(8))) unsigned short u16x8;
typedef __attribute__((ext_vector_type(4))) float f32x4;

__device__ __forceinline__ unsigned short f2bf(float x) {
    unsigned int u = __float_as_uint(x);
    u += 0x7fffu + ((u >> 16) & 1u);   // round-to-nearest-even
    return (unsigned short)(u >> 16);
}

__device__ __forceinline__ u16x8 pack8(float4 a, float4 b) {
    u16x8 o;
    o[0] = f2bf(a.x); o[1] = f2bf(a.y); o[2] = f2bf(a.z); o[3] = f2bf(a.w);
    o[4] = f2bf(b.x); o[5] = f2bf(b.y); o[6] = f2bf(b.z); o[7] = f2bf(b.w);
    return o;
}

// ---------------- fused: histogram + input-fragment prep (both input sets) ----------------
// inb: 16B chunk ch = (nr*8 + kc)*64 + l holds row nr*16+(l&15)
// (rows 0..127 inputs, 128..255 inputs2), k = kc*32 + (l>>4)*8 + j.
__global__ __launch_bounds__(256) void hist_prep_kernel(
    const int* __restrict__ labels, int* __restrict__ counts,
    const float* __restrict__ in1, const float* __restrict__ in2,
    unsigned short* __restrict__ inb)
{
    int bid = blockIdx.x;
    if (bid < HIST_BLOCKS) {
        int n = bid * 256 + threadIdx.x;
        if (n < NN) atomicAdd(&counts[labels[n]], 1);
    } else {
        int ch = (bid - HIST_BLOCKS) * 256 + threadIdx.x;  // 0..8191
        if (ch >= 8192) return;
        int l  = ch & 63;
        int kc = (ch >> 6) & 7;
        int nr = ch >> 9;
        int row = nr * 16 + (l & 15);
        const float* src = (row < BB) ? (in1 + (size_t)row * DD)
                                      : (in2 + (size_t)(row - BB) * DD);
        int k0 = kc * 32 + ((l >> 4) << 3);
        u16x8 o;
        #pragma unroll
        for (int j = 0; j < 8; ++j) o[j] = f2bf(src[k0 + j]);
        *(u16x8*)(inb + (size_t)ch * 8) = o;
    }
}

// one block, 256 threads, exclusive scan over 2048 (padded) counts; also zeroes out
__global__ __launch_bounds__(256) void scan_kernel(const int* __restrict__ counts,
                                                   int* __restrict__ offsets,
                                                   int* __restrict__ cursor,
                                                   float* __restrict__ out) {
    const int PT = 8;
    int tid = threadIdx.x;
    if (tid == 0) { out[0] = 0.f; out[1] = 0.f; }
    int vals[PT];
    int tot = 0;
    #pragma unroll
    for (int i = 0; i < PT; ++i) {
        int c = tid * PT + i;
        vals[i] = (c < CC) ? counts[c] : 0;
        tot += vals[i];
    }
    __shared__ int sh[256];
    sh[tid] = tot;
    __syncthreads();
    for (int ofs = 1; ofs < 256; ofs <<= 1) {
        int v = (tid >= ofs) ? sh[tid - ofs] : 0;
        __syncthreads();
        sh[tid] += v;
        __syncthreads();
    }
    int run = sh[tid] - tot;
    #pragma unroll
    for (int i = 0; i < PT; ++i) {
        int c = tid * PT + i;
        if (c < CC) { offsets[c] = run; cursor[c] = run; }
        run += vals[i];
    }
}

// ---------------- scatter: class-sorted index + class id lists (no data copy) ----------------
__global__ void scatter_kernel(const int* __restrict__ labels, int* __restrict__ cursor,
                               int* __restrict__ sorted_idx, int* __restrict__ cls_sorted) {
    int n = blockIdx.x * 256 + threadIdx.x;
    if (n < NN) {
        int c = labels[n];
        int p = atomicAdd(&cursor[c], 1);
        sorted_idx[p] = n;
        cls_sorted[p] = c;
    }
}

// ---------------- heavy kernel: one streaming pass, segment partials, NO atomics ----------------
// Grid = NTILES x 256 (4 waves). Block t: sorted rows [64t, 64t+64).
// Stage: gather 64 f32 rows via sorted_idx (coalesced 1KB granules), convert bf16,
// ds_write into fragment-order LDS (frag (ma,kc)=1KB; chunk c holds row 16ma+((c&15)^kc),
// k-slice c>>4) -> conflict-free read path (r8/r9-proven).
// Segments: wave0 computes per-row slot ids via __ballot boundary popcount; writes
// seg_class[t*8+s]. Two phases over the SAME A-tile:
//   ph0: cols = inputs   -> per-(tile,slot,col) max/min/sum partials (plain stores)
//   ph1: cols = inputs2  -> sum partials only
// Logit dump stride 132 (bank-spread); scan = 1 thread/col over 64 rows.
__global__ __launch_bounds__(256, 2) void gemm_seg(
    const float* __restrict__ features, const unsigned short* __restrict__ inb,
    const int* __restrict__ sorted_idx, const int* __restrict__ cls_sorted,
    float* __restrict__ part_max, float* __restrict__ part_min,
    float* __restrict__ part_sA, float* __restrict__ part_sB,
    int* __restrict__ seg_class)
{
    const int tid = threadIdx.x;
    const int w   = tid >> 6;
    const int l   = tid & 63;
    const int t   = blockIdx.x;
    const int r0  = t * 64;

    __shared__ __align__(16) char ldsA[32768];       // A tile, bf16 fragment order
    __shared__ float logit[64 * 132];                // f32 logits, padded stride
    __shared__ int cls_l[64];
    __shared__ int slot_l[64];

    // init seg_class for this tile (before barrier; boundary writers run after)
    if (tid >= 128 && tid < 128 + MAXSEG) seg_class[t * MAXSEG + (tid - 128)] = -1;

    // stage class ids
    if (tid < 64) {
        int gr = r0 + tid;
        cls_l[tid] = (gr < NN) ? cls_sorted[gr] : -1;
    }

    // stage A: thread = (row = tid>>2, q = tid&3); 4 sub-chunks of 16 f32 each
    {
        int row = tid >> 2, q = tid & 3;
        int gr  = min(r0 + row, NN - 1);
        int n   = sorted_idx[gr];
        const float* src = features + (size_t)n * DD;
        #pragma unroll
        for (int j = 0; j < 4; ++j) {
            int k0 = j * 64 + q * 16;
            float4 v0 = *(const float4*)(src + k0);
            float4 v1 = *(const float4*)(src + k0 + 4);
            float4 v2 = *(const float4*)(src + k0 + 8);
            float4 v3 = *(const float4*)(src + k0 + 12);
            int kc = j * 2 + (q >> 1);
            int x  = (row & 15) ^ kc;
            int s0 = (q & 1) * 2;
            int base = (((row >> 4) * 8 + kc) << 10);
            *(u16x8*)(&ldsA[0] + base + (((s0 << 4) | x) << 4))       = pack8(v0, v1);
            *(u16x8*)(&ldsA[0] + base + ((((s0 + 1) << 4) | x) << 4)) = pack8(v2, v3);
        }
    }
    __syncthreads();

    // slot ids (wave 0): boundary ballot + prefix popcount; record slot->class
    if (tid < 64) {
        bool bnd = (tid > 0) && (cls_l[tid] != cls_l[tid - 1]);
        unsigned long long mask = __ballot(bnd);
        int s = __popcll(mask & ((2ull << tid) - 1ull));
        slot_l[tid] = s;
        if ((bnd || tid == 0) && s < MAXSEG && cls_l[tid] >= 0)
            seg_class[t * MAXSEG + s] = cls_l[tid];
    }

    #pragma unroll
    for (int ph = 0; ph < 2; ++ph) {
        // B fragments for this phase's 128 cols (L2-hot inb, coalesced 1KB/load)
        bf16x8 bfr[16];
        #pragma unroll
        for (int kc = 0; kc < 8; ++kc)
            #pragma unroll
            for (int nb = 0; nb < 2; ++nb) {
                int nr = ph * 8 + 2 * w + nb;
                bfr[kc * 2 + nb] = *(const bf16x8*)(inb + (((size_t)(nr * 8 + kc) * 64 + l) << 3));
            }

        f32x4 acc[4][2];
        #pragma unroll
        for (int ma = 0; ma < 4; ++ma)
            #pragma unroll
            for (int nb = 0; nb < 2; ++nb)
                acc[ma][nb] = (f32x4){0.f, 0.f, 0.f, 0.f};

        __builtin_amdgcn_s_setprio(1);
        #pragma unroll
        for (int kc = 0; kc < 8; ++kc) {
            int lx = (l ^ kc) << 4;
            #pragma unroll
            for (int ma = 0; ma < 4; ++ma) {
                bf16x8 a = *(const bf16x8*)(&ldsA[0] + ((ma * 8 + kc) << 10) + lx);
                acc[ma][0] = __builtin_amdgcn_mfma_f32_16x16x32_bf16(a, bfr[kc * 2 + 0], acc[ma][0], 0, 0, 0);
                acc[ma][1] = __builtin_amdgcn_mfma_f32_16x16x32_bf16(a, bfr[kc * 2 + 1], acc[ma][1], 0, 0, 0);
            }
        }
        __builtin_amdgcn_s_setprio(0);

        // dump logits: row = 16ma+4*(l>>4)+reg, col = 32w+16nb+(l&15)
        {
            int m = l & 15, h = l >> 4;
            #pragma unroll
            for (int ma = 0; ma < 4; ++ma)
                #pragma unroll
                for (int nb = 0; nb < 2; ++nb)
                    #pragma unroll
                    for (int reg = 0; reg < 4; ++reg)
                        logit[(16 * ma + 4 * h + reg) * 132 + (32 * w + 16 * nb + m)] = acc[ma][nb][reg];
        }
        __syncthreads();   // logits + slot_l visible

        // segment scan: 1 thread per col over 64 rows; plain stores per segment
        if (tid < 128) {
            int col = tid;
            int cs = slot_l[0];
            float v0 = logit[col];
            float mx = v0, mn = v0, sm = v0;
            #pragma unroll 4
            for (int r = 1; r < 64; ++r) {
                float v = logit[r * 132 + col];
                int s = slot_l[r];
                if (s != cs) {
                    if (cs < MAXSEG) {
                        size_t p = (size_t)(t * MAXSEG + cs) * 128 + col;
                        if (ph == 0) { part_max[p] = mx; part_min[p] = mn; part_sA[p] = sm; }
                        else         { part_sB[p] = sm; }
                    }
                    cs = s; mx = v; mn = v; sm = v;
                } else {
                    mx = fmaxf(mx, v);
                    mn = fminf(mn, v);
                    sm += v;
                }
            }
            if (cs < MAXSEG) {
                size_t p = (size_t)(t * MAXSEG + cs) * 128 + col;
                if (ph == 0) { part_max[p] = mx; part_min[p] = mn; part_sA[p] = sm; }
                else         { part_sB[p] = sm; }
            }
        }
        __syncthreads();   // protect logit before next phase's dump
    }
}

// ---------------- combine: fold per-tile partials into per-class results ----------------
// Block = class c (2000), 128 threads = batch col. Classes are contiguous in the
// sorted order: tiles t0..t1 cover class c; find its slot via seg_class match.
__global__ __launch_bounds__(128) void combine_kernel(
    const float* __restrict__ part_max, const float* __restrict__ part_min,
    const float* __restrict__ part_sA, const float* __restrict__ part_sB,
    const int* __restrict__ seg_class,
    const int* __restrict__ offsets, const int* __restrict__ counts,
    float* __restrict__ gmax, float* __restrict__ gmin,
    float* __restrict__ simA, float* __restrict__ simB)
{
    const int c   = blockIdx.x;
    const int col = threadIdx.x;
    const int cnt = counts[c];
    if (cnt <= 0) {
        gmax[(size_t)c * 128 + col] = 0.f;
        gmin[(size_t)c * 128 + col] = 0.f;
        simA[(size_t)c * 128 + col] = 0.f;
        simB[(size_t)c * 128 + col] = 0.f;
        return;
    }
    const int off = offsets[c];
    const int t0 = off >> 6, t1 = (off + cnt - 1) >> 6;

    float mx = -3.4e38f, mn = 3.4e38f, sA = 0.f, sB = 0.f;
    for (int t = t0; t <= t1; ++t) {
        int s = -1;
        #pragma unroll
        for (int i = 0; i < MAXSEG; ++i)
            if (seg_class[t * MAXSEG + i] == c) s = i;
        if (s >= 0) {
            size_t p = (size_t)(t * MAXSEG + s) * 128 + col;
            mx = fmaxf(mx, part_max[p]);
            mn = fminf(mn, part_min[p]);
            sA += part_sA[p];
            sB += part_sB[p];
        }
    }
    float icnt = INVTEMP / (float)cnt;
    gmax[(size_t)c * 128 + col] = mx * INVTEMP;
    gmin[(size_t)c * 128 + col] = mn * INVTEMP;
    simA[(size_t)c * 128 + col] = sA * icnt;
    simB[(size_t)c * 128 + col] = sB * icnt;
}

// ---------------- finalize: losses ----------------

__device__ __forceinline__ float blk_reduce_sum(float v) {
    __shared__ float sh[4];
    int lane = threadIdx.x & 63, w = threadIdx.x >> 6;
    #pragma unroll
    for (int o = 32; o; o >>= 1) v += __shfl_down(v, o, 64);
    __syncthreads();
    if (lane == 0) sh[w] = v;
    __syncthreads();
    return sh[0] + sh[1] + sh[2] + sh[3];
}

__device__ __forceinline__ float blk_reduce_max(float v) {
    __shared__ float sh[4];
    int lane = threadIdx.x & 63, w = threadIdx.x >> 6;
    #pragma unroll
    for (int o = 32; o; o >>= 1) v = fmaxf(v, __shfl_down(v, o, 64));
    __syncthreads();
    if (lane == 0) sh[w] = v;
    __syncthreads();
    return fmaxf(fmaxf(sh[0], sh[1]), fmaxf(sh[2], sh[3]));
}

__global__ __launch_bounds__(256) void finalize_kernel(
    const float* __restrict__ gmax, const float* __restrict__ gmin,
    const float* __restrict__ simA, const float* __restrict__ simB,
    const int* __restrict__ counts, const int* __restrict__ labels,
    const int* __restrict__ indexes, float* __restrict__ out)
{
    const int b   = blockIdx.x;
    const int tid = threadIdx.x;
    const int tgt = labels[indexes[b]];

    __shared__ float sh_etgt;
    float local = 0.f;
    for (int c = tid; c < CC; c += 256) {
        float e = 0.f;
        if (counts[c] > 0) {
            float v = (c == tgt) ? gmin[(size_t)c * 128 + b] : gmax[(size_t)c * 128 + b];
            e = expf(v);
        }
        local += e;
        if (c == tgt) sh_etgt = e;
    }
    float sum_e = blk_reduce_sum(local);
    float etgt = sh_etgt;
    float loss_con_b = -logf(etgt / (sum_e + EPSV) + EPSV);

    __shared__ float a1[SS], a2[SS];
    for (int c = tid; c < SS; c += 256) {
        a1[c] = simA[(size_t)c * 128 + b];
        a2[c] = simB[(size_t)c * 128 + b];
    }
    __syncthreads();
    float m1 = -3.4e38f, m2 = -3.4e38f;
    for (int c = tid; c < SS; c += 256) { m1 = fmaxf(m1, a1[c]); m2 = fmaxf(m2, a2[c]); }
    m1 = blk_reduce_max(m1);
    m2 = blk_reduce_max(m2);
    float s1 = 0.f, s2 = 0.f;
    for (int c = tid; c < SS; c += 256) { s1 += expf(a1[c] - m1); s2 += expf(a2[c] - m2); }
    s1 = blk_reduce_sum(s1);
    s2 = blk_reduce_sum(s2);
    float inv1 = 1.f / s1, inv2 = 1.f / s2;
    float dsum = 0.f;
    for (int c = tid; c < SS; c += 256) {
        float d = expf(a1[c] - m1) * inv1 - expf(a2[c] - m2) * inv2;
        dsum += d * d;
    }
    dsum = blk_reduce_sum(dsum);
    if (tid == 0) {
        atomicAdd(&out[0], loss_con_b * (1.0f / (float)BB));
        atomicAdd(&out[1], dsum * (1.0f / (float)SS));
    }
}

// ---------------- launch ----------------

extern "C" void kernel_launch(void* const* d_in, const int* in_sizes, int n_in,
                              void* d_out, int out_size, void* d_ws, size_t ws_size,
                              hipStream_t stream) {
    const float* inputs   = (const float*)d_in[0];
    const float* inputs2  = (const float*)d_in[1];
    const float* features = (const float*)d_in[2];
    const int*   labels   = (const int*)d_in[3];
    const int*   indexes  = (const int*)d_in[4];

    float* out = (float*)d_out;

    // workspace layout (int-element offsets)
    int* wsi = (int*)d_ws;
    int* counts  = wsi;                                   // [0, 2048)
    int* offsets = wsi + 2048;                            // [2048, 4096)
    int* cursor  = wsi + 4096;                            // [4096, 6144)
    unsigned short* inb = (unsigned short*)(wsi + 6144);  // 65536 ushorts -> [6144, 38912)
    int* sorted  = wsi + 38912;                           // [38912, 138912)
    int* clss    = wsi + 138912;                          // [138912, 238912)
    int* segcls  = wsi + 238912;                          // NTILES*8 = 12504 -> [238912, 251416)
    float* part_max = (float*)(wsi + 251416);             // NTILES*8*128 = 1600512 each
    float* part_min = part_max + (size_t)NTILES * MAXSEG * 128;
    float* part_sA  = part_min + (size_t)NTILES * MAXSEG * 128;
    float* part_sB  = part_sA  + (size_t)NTILES * MAXSEG * 128;
    float* gmax = part_sB + (size_t)NTILES * MAXSEG * 128; // CC*128 each
    float* gmin = gmax + (size_t)CC * 128;
    float* simA = gmin + (size_t)CC * 128;
    float* simB = simA + (size_t)CC * 128;

    hipMemsetAsync(counts, 0, 2048 * sizeof(int), stream);

    hist_prep_kernel<<<HIST_BLOCKS + PREP_BLOCKS, 256, 0, stream>>>(
        labels, counts, inputs, inputs2, inb);
    scan_kernel<<<1, 256, 0, stream>>>(counts, offsets, cursor, out);
    scatter_kernel<<<(NN + 255) / 256, 256, 0, stream>>>(labels, cursor, sorted, clss);
    gemm_seg<<<NTILES, 256, 0, stream>>>(features, inb, sorted, clss,
                                         part_max, part_min, part_sA, part_sB, segcls);
    combine_kernel<<<CC, 128, 0, stream>>>(part_max, part_min, part_sA, part_sB, segcls,
                                           offsets, counts, gmax, gmin, simA, simB);
    finalize_kernel<<<BB, 256, 0, stream>>>(gmax, gmin, simA, simB, counts,
                                            labels, indexes, out);
}